// Round 11
// baseline (284.933 us; speedup 1.0000x reference)
//
#include <hip/hip_runtime.h>

// Problem constants (from reference setup_inputs)
#define NATOMS 32768
#define NFEAT 1920
#define HIDDEN 256
#define NSPEC 4
#define NSTRUCT 512
#define BK 32
#define MT128 260                // 128-row m-tiles (4 species padded to x128)
#define MPAD (MT128 * 128)       // 33280
#define KS 4                     // K-split chunks for layer 1
#define KC (NFEAT / KS)          // 480
#define NBLK1 (MT128 * KS)       // 1040 layer-1 blocks
#define NBLK2 ((MPAD / 64) * 2)  // 1040 layer-2/3 blocks (64-row tile, n-half)

typedef __bf16 bf16x8 __attribute__((ext_vector_type(8)));
typedef float f32x4 __attribute__((ext_vector_type(4)));
typedef float f4v __attribute__((ext_vector_type(4)));
typedef unsigned short us4 __attribute__((ext_vector_type(4)));

// Workspace layout (bytes). W2t/W3t alias W1t (transposed AFTER layer 1).
#define WS_INTS 0                                        // ints[0..3] counts,[4..7] cursors,[8..12] off; bytes 128..191 zero-stub
#define WS_PERM 256
#define WS_W1T (WS_PERM + MPAD * 4)
#define WS_W2T WS_W1T                                    // alias (post-L1)
#define WS_W3T (WS_W2T + NSPEC * HIDDEN * HIDDEN * 2)    // still inside W1t
#define WS_W4T (WS_W1T + NSPEC * HIDDEN * NFEAT * 2)
#define WS_H1  (WS_W4T + 4096)                           // bf16 [MPAD][256] (L3 out)
#define WS_H2  (WS_H1 + (size_t)MPAD * HIDDEN * 2)       // bf16 [MPAD][256] (L2 out)
#define WS_HP  (WS_H2 + (size_t)MPAD * HIDDEN * 2)       // f32  [MPAD][256] (L1 partial acc)
#define WS_END (WS_HP + (size_t)MPAD * HIDDEN * 4)       // ~72 MB total

__device__ __forceinline__ unsigned short f2bf(float f) {
  unsigned int u = __float_as_uint(f);
  u += 0x7fffu + ((u >> 16) & 1u);           // round-to-nearest-even
  return (unsigned short)(u >> 16);
}
__device__ __forceinline__ float bf2f(unsigned short s) {
  return __uint_as_float(((unsigned int)s) << 16);
}
__device__ __forceinline__ float silu_n(float x) {
  return (x / (1.f + __expf(-x))) * 1.6765f; // variance-preserving SiLU
}

// Direct global->LDS async copy, 16 B per lane. LDS dest = uniform base + lane*16.
__device__ __forceinline__ void gll16(const void* g, void* l) {
  __builtin_amdgcn_global_load_lds(
      (const __attribute__((address_space(1))) void*)g,
      (__attribute__((address_space(3))) void*)l, 16, 0, 0);
}

// ---- prep kernels -------------------------------------------------------

__global__ void k_init(int* ints, int* perm, float* out) {
  int i = blockIdx.x * blockDim.x + threadIdx.x;
  if (i < MPAD) perm[i] = -1;
  if (i < NSTRUCT) out[i] = 0.f;
  if (i < 8) ints[i] = 0;
  if (i >= 32 && i < 48) ((float*)ints)[i] = 0.f;   // zero-stub for padded gather rows
}

__global__ void k_zero(float* p) {                   // zero Hp (f4 per thread)
  int i = blockIdx.x * 256 + threadIdx.x;
  f4v z = {0.f, 0.f, 0.f, 0.f};
  ((f4v*)p)[i] = z;
}

// Block-aggregated species count: ballots -> LDS -> 4 atomics per block.
__global__ void k_count(const int* __restrict__ species, int* counts) {
  __shared__ int c[NSPEC];
  int tid = threadIdx.x;
  if (tid < NSPEC) c[tid] = 0;
  __syncthreads();
  int s = species[blockIdx.x * 256 + tid];
  int lane = tid & 63;
#pragma unroll
  for (int sp = 0; sp < NSPEC; ++sp) {
    unsigned long long m = __ballot(s == sp);
    if (lane == 0 && m) atomicAdd(&c[sp], __popcll(m));
  }
  __syncthreads();
  if (tid < NSPEC && c[tid]) atomicAdd(&counts[tid], c[tid]);
}

__global__ void k_offsets(int* ints) {
  int* counts = ints;
  int* cursors = ints + 4;
  int* off = ints + 8;
  off[0] = 0;
  for (int s = 0; s < NSPEC; ++s) {
    off[s + 1] = off[s] + ((counts[s] + 127) & ~127);   // pad to 128 (L1 BM)
    cursors[s] = off[s];
  }
}

// Block-aggregated scatter: one range-reserving atomic per (block, species).
__global__ void k_scatter(const int* __restrict__ species, int* ints, int* perm) {
  __shared__ int cnt[4][NSPEC];   // [wave][species]
  __shared__ int base[NSPEC];
  int tid = threadIdx.x;
  int w = tid >> 6, lane = tid & 63;
  int i = blockIdx.x * 256 + tid;
  int s = species[i];
  unsigned long long m0 = __ballot(s == 0);
  unsigned long long m1 = __ballot(s == 1);
  unsigned long long m2 = __ballot(s == 2);
  unsigned long long m3 = __ballot(s == 3);
  if (lane == 0) {
    cnt[w][0] = __popcll(m0);
    cnt[w][1] = __popcll(m1);
    cnt[w][2] = __popcll(m2);
    cnt[w][3] = __popcll(m3);
  }
  __syncthreads();
  if (tid < NSPEC) {
    int t = cnt[0][tid] + cnt[1][tid] + cnt[2][tid] + cnt[3][tid];
    base[tid] = t ? atomicAdd(&ints[4 + tid], t) : 0;
  }
  __syncthreads();
  unsigned long long mm = (s == 0) ? m0 : (s == 1) ? m1 : (s == 2) ? m2 : m3;
  int pos = base[s] + __popcll(mm & ((1ull << lane) - 1ull));
#pragma unroll
  for (int ww = 0; ww < 4; ++ww)
    if (ww < w) pos += cnt[ww][s];
  perm[pos] = i;
}

// f32 [S][K][N] -> bf16 [S][N][K]  (64x64 LDS tiled transpose)
__global__ void k_transpose(const float* __restrict__ src, unsigned short* __restrict__ dst,
                            int K, int N) {
  __shared__ unsigned short T[64][72];
  int ntN = N >> 6, ntK = K >> 6;
  int per = ntK * ntN;
  int b = blockIdx.x;
  int s = b / per, rem = b % per;
  int k0 = (rem / ntN) << 6;
  int n0 = (rem % ntN) << 6;
  int tid = threadIdx.x;
  int r = tid >> 2, cb = (tid & 3) << 4;
  const float* p = src + ((size_t)s * K + k0 + r) * N + n0 + cb;
#pragma unroll
  for (int j = 0; j < 16; j += 4) {
    f4v v = *(const f4v*)(p + j);
#pragma unroll
    for (int e = 0; e < 4; ++e) T[r][cb + j + e] = f2bf(v[e]);
  }
  __syncthreads();
  unsigned short* drow = dst + ((size_t)s * N + n0 + r) * K + k0 + cb;
#pragma unroll
  for (int j = 0; j < 4; ++j) {
    us4 o;
#pragma unroll
    for (int e = 0; e < 4; ++e) o[e] = T[cb + j * 4 + e][r];
    *(us4*)(drow + j * 4) = o;
  }
}

__global__ void k_w4(const float* __restrict__ src, unsigned short* __restrict__ dst) {
  int i = blockIdx.x * 256 + threadIdx.x;   // 4*256 elems
  dst[i] = f2bf(src[i]);
}

// ---- layer 1: K-split read-once GEMM -----------------------------------
// Staged-byte-minimal shape (R5-R10 showed the gll16 path is throughput-bound
// at ~6 TB/s delivered): BM=128 x BN=256 (A read ONCE, B restaged only
// M/128 times) x KS=4 K-chunks => 1040 blocks (2 residents/CU at 64 KB LDS).
// Staged total = 254 MB A(f32) + 254 MB B vs R8's 1014 MB.
// Partials: f32 atomicAdd into Hp (zeroed per call); silu+bf16 happen in L2.
// XCD map: kc = xcd>>1 -> one k-chunk's whole B slice (~1 MB) lives in one
// XCD pair's L2.
__global__ __launch_bounds__(512) void k_l1ks(
    const float* __restrict__ xf, const unsigned short* __restrict__ Wt,
    float* __restrict__ Hp, const int* __restrict__ perm,
    const int* __restrict__ off, const float* __restrict__ zs, float scale) {
  __shared__ __align__(16) unsigned short Asl[2 * 8192];  // 2 x 16 KB (f32 128x32)
  __shared__ __align__(16) unsigned short Bsl[2 * 8192];  // 2 x 16 KB (bf16 256x32)
  float* af = (float*)Asl;
  unsigned short* bl = Bsl;

  int xcd = blockIdx.x & 7, i = blockIdx.x >> 3;   // grid 1040 = 8 x 130
  int kc = xcd >> 1;
  int mt = (i << 1) | (xcd & 1);
  int rowbase = mt * 128;
  int kbase = kc * KC;

  int tid = threadIdx.x;
  int w = tid >> 6, lane = tid & 63;
  int wr = w >> 2, wc = w & 3;             // 2x4 waves of 64x64 output

  int sp;
  if (rowbase < off[1]) sp = 0;
  else if (rowbase < off[2]) sp = 1;
  else if (rowbase < off[3]) sp = 2;
  else sp = 3;

  // B: 256 rows x 64 B = 16 chunks of 1 KB; wave w stages chunks 2w,2w+1.
  const unsigned short* srcB[2];
  int ldsB[2];
#pragma unroll
  for (int qq = 0; qq < 2; ++qq) {
    int c = w * 2 + qq;
    int row = c * 16 + (lane >> 2);
    int slot = (lane & 3) ^ ((row >> 2) & 3);
    srcB[qq] = Wt + ((size_t)(sp * HIDDEN + row)) * NFEAT + kbase + slot * 8;
    ldsB[qq] = c * 512;                    // shorts
  }
  // A (f32): 128 rows x 128 B = 16 chunks of 1 KB; wave w: chunks 2w,2w+1.
  const float* srcA[2];
  int ldsA[2];
#pragma unroll
  for (int qq = 0; qq < 2; ++qq) {
    int c = w * 2 + qq;
    int row = c * 8 + (lane >> 3);
    int slot = (lane & 7) ^ (row & 7);
    long as = perm[rowbase + row];
    srcA[qq] = (as >= 0) ? (xf + (size_t)as * NFEAT + kbase + slot * 4) : nullptr;
    ldsA[qq] = c * 256;                    // floats
  }

  auto STAGE = [&](int b, int t) {
#pragma unroll
    for (int qq = 0; qq < 2; ++qq) {
      const float* s = srcA[qq] ? srcA[qq] + t * BK : zs;
      gll16(s, af + b * 4096 + ldsA[qq]);
    }
#pragma unroll
    for (int qq = 0; qq < 2; ++qq)
      gll16(srcB[qq] + t * BK, bl + b * 8192 + ldsB[qq]);
  };

  f32x4 zero4 = {0.f, 0.f, 0.f, 0.f};
  f32x4 acc[4][4];
#pragma unroll
  for (int m = 0; m < 4; ++m)
#pragma unroll
    for (int n = 0; n < 4; ++n) acc[m][n] = zero4;

  int lr = lane & 15, lg = lane >> 4;
  constexpr int NT = KC / BK;              // 15

  STAGE(0, 0);
  __syncthreads();
  int buf = 0;
  for (int t = 0; t < NT; ++t) {
    if (t + 1 < NT) STAGE(buf ^ 1, t + 1);

    bf16x8 a[4], b[4];
#pragma unroll
    for (int m = 0; m < 4; ++m) {
      int row = wr * 64 + m * 16 + lr;
      const float* base = af + buf * 4096 + row * 32;
      f4v x0 = *(const f4v*)(base + (((lg << 1) ^ (row & 7)) << 2));
      f4v x1 = *(const f4v*)(base + ((((lg << 1) | 1) ^ (row & 7)) << 2));
      unsigned r01, r23, r45, r67;
      asm("v_cvt_pk_bf16_f32 %0, %1, %2" : "=v"(r01) : "v"(x0[0]), "v"(x0[1]));
      asm("v_cvt_pk_bf16_f32 %0, %1, %2" : "=v"(r23) : "v"(x0[2]), "v"(x0[3]));
      asm("v_cvt_pk_bf16_f32 %0, %1, %2" : "=v"(r45) : "v"(x1[0]), "v"(x1[1]));
      asm("v_cvt_pk_bf16_f32 %0, %1, %2" : "=v"(r67) : "v"(x1[2]), "v"(x1[3]));
      union { unsigned u[4]; bf16x8 v; } cv = {{r01, r23, r45, r67}};
      a[m] = cv.v;
    }
#pragma unroll
    for (int n = 0; n < 4; ++n) {
      int row = wc * 64 + n * 16 + lr;
      b[n] = *(const bf16x8*)(bl + buf * 8192 + row * 32 +
                              ((lg ^ ((row >> 2) & 3)) << 3));
    }
#pragma unroll
    for (int m = 0; m < 4; ++m)
#pragma unroll
      for (int n = 0; n < 4; ++n)
        acc[m][n] = __builtin_amdgcn_mfma_f32_16x16x32_bf16(a[m], b[n], acc[m][n], 0, 0, 0);

    __syncthreads();
    buf ^= 1;
  }

  // epilogue: scaled f32 partial -> atomicAdd into Hp
#pragma unroll
  for (int m = 0; m < 4; ++m)
#pragma unroll
    for (int n = 0; n < 4; ++n)
#pragma unroll
      for (int rr = 0; rr < 4; ++rr)
        atomicAdd(&Hp[(size_t)(rowbase + wr * 64 + m * 16 + lg * 4 + rr) * HIDDEN +
                      wc * 64 + n * 16 + lr],
                  acc[m][n][rr] * scale);
}

// ---- layers 2/3: BM=64 x BN=128, 2-buffer drain (R8-proven delivery) ----
// MODE 1: A = f32 Hp, silu_n applied at fragment load (layer 2).
// MODE 0: A = bf16 row-major (layer 3).
template <int MODE>
__global__ __launch_bounds__(256) void k_mlp2(
    const float* __restrict__ xf, const unsigned short* __restrict__ xb,
    const unsigned short* __restrict__ Wt, unsigned short* __restrict__ Hout,
    const int* __restrict__ off, float scale) {
  constexpr int K = HIDDEN;
  __shared__ __align__(16) unsigned short Asl[MODE ? 2 * 4096 : 2 * 2048];
  __shared__ __align__(16) unsigned short Bsl[2 * 4096];
  float* af = (float*)Asl;
  unsigned short* ab = Asl;
  unsigned short* bl = Bsl;

  int nwg = gridDim.x;
  int xcd = blockIdx.x & 7, idx = blockIdx.x >> 3;
  int q = nwg >> 3, r = nwg & 7;
  int lb = (xcd < r ? xcd * (q + 1) : r * (q + 1) + (xcd - r) * q) + idx;
  int mt = lb >> 1, bn = lb & 1;

  int rowbase = mt * 64;
  int tid = threadIdx.x;
  int w = tid >> 6, lane = tid & 63;
  int wr = w >> 1, wc = w & 1;

  int sp;
  if (rowbase < off[1]) sp = 0;
  else if (rowbase < off[2]) sp = 1;
  else if (rowbase < off[3]) sp = 2;
  else sp = 3;

  const unsigned short* srcB[2];
  int ldsB[2];
#pragma unroll
  for (int qq = 0; qq < 2; ++qq) {
    int c = w * 2 + qq;
    int row = c * 16 + (lane >> 2);
    int slot = (lane & 3) ^ ((row >> 2) & 3);
    srcB[qq] = Wt + ((size_t)(sp * HIDDEN + bn * 128 + row)) * K + slot * 8;
    ldsB[qq] = c * 512;
  }
  const float* srcAf[2];
  const unsigned short* srcA1 = nullptr;
  int ldsAf[2], ldsA1 = 0;
  if constexpr (MODE) {
    // f32 A: 64 rows x 128 B = 8 chunks of 1 KB; wave w: chunks 2w,2w+1.
#pragma unroll
    for (int qq = 0; qq < 2; ++qq) {
      int c = w * 2 + qq;
      int row = c * 8 + (lane >> 3);
      int slot = (lane & 7) ^ (row & 7);
      srcAf[qq] = xf + (size_t)(rowbase + row) * K + slot * 4;
      ldsAf[qq] = c * 256;                 // floats
    }
  } else {
    int row = w * 16 + (lane >> 2);
    int slot = (lane & 3) ^ ((row >> 2) & 3);
    srcA1 = xb + ((size_t)(rowbase + row)) * K + slot * 8;
    ldsA1 = w * 512;
  }

  auto STAGE = [&](int b, int t) {
    if constexpr (MODE) {
#pragma unroll
      for (int qq = 0; qq < 2; ++qq)
        gll16(srcAf[qq] + t * BK, af + b * 2048 + ldsAf[qq]);
    } else {
      gll16(srcA1 + t * BK, ab + b * 2048 + ldsA1);
    }
#pragma unroll
    for (int qq = 0; qq < 2; ++qq)
      gll16(srcB[qq] + t * BK, bl + b * 4096 + ldsB[qq]);
  };

  f32x4 zero4 = {0.f, 0.f, 0.f, 0.f};
  f32x4 acc[2][4];
#pragma unroll
  for (int m = 0; m < 2; ++m)
#pragma unroll
    for (int n = 0; n < 4; ++n) acc[m][n] = zero4;

  int lr = lane & 15, lg = lane >> 4;
  constexpr int NT = K / BK;

  STAGE(0, 0);
  __syncthreads();
  int buf = 0;
  for (int t = 0; t < NT; ++t) {
    if (t + 1 < NT) STAGE(buf ^ 1, t + 1);

    bf16x8 a[2], b[4];
#pragma unroll
    for (int m = 0; m < 2; ++m) {
      int row = wr * 32 + m * 16 + lr;
      if constexpr (MODE) {
        const float* base = af + buf * 2048 + row * 32;
        f4v x0 = *(const f4v*)(base + (((lg << 1) ^ (row & 7)) << 2));
        f4v x1 = *(const f4v*)(base + ((((lg << 1) | 1) ^ (row & 7)) << 2));
        float s0 = silu_n(x0[0]), s1v = silu_n(x0[1]), s2v = silu_n(x0[2]), s3 = silu_n(x0[3]);
        float s4 = silu_n(x1[0]), s5 = silu_n(x1[1]), s6 = silu_n(x1[2]), s7 = silu_n(x1[3]);
        unsigned r01, r23, r45, r67;
        asm("v_cvt_pk_bf16_f32 %0, %1, %2" : "=v"(r01) : "v"(s0), "v"(s1v));
        asm("v_cvt_pk_bf16_f32 %0, %1, %2" : "=v"(r23) : "v"(s2v), "v"(s3));
        asm("v_cvt_pk_bf16_f32 %0, %1, %2" : "=v"(r45) : "v"(s4), "v"(s5));
        asm("v_cvt_pk_bf16_f32 %0, %1, %2" : "=v"(r67) : "v"(s6), "v"(s7));
        union { unsigned u[4]; bf16x8 v; } cv = {{r01, r23, r45, r67}};
        a[m] = cv.v;
      } else {
        a[m] = *(const bf16x8*)(ab + buf * 2048 + row * 32 +
                                ((lg ^ ((row >> 2) & 3)) << 3));
      }
    }
#pragma unroll
    for (int n = 0; n < 4; ++n) {
      int row = wc * 64 + n * 16 + lr;
      b[n] = *(const bf16x8*)(bl + buf * 4096 + row * 32 +
                              ((lg ^ ((row >> 2) & 3)) << 3));
    }
#pragma unroll
    for (int m = 0; m < 2; ++m)
#pragma unroll
      for (int n = 0; n < 4; ++n)
        acc[m][n] = __builtin_amdgcn_mfma_f32_16x16x32_bf16(a[m], b[n], acc[m][n], 0, 0, 0);

    __syncthreads();
    buf ^= 1;
  }

#pragma unroll
  for (int m = 0; m < 2; ++m)
#pragma unroll
    for (int n = 0; n < 4; ++n)
#pragma unroll
      for (int rr = 0; rr < 4; ++rr) {
        float v = acc[m][n][rr] * scale;
        Hout[(size_t)(rowbase + wr * 32 + m * 16 + lg * 4 + rr) * HIDDEN +
             bn * 128 + wc * 64 + n * 16 + lr] = f2bf(silu_n(v));
      }
}

// ---- layer 4 + segment reduction ---------------------------------------
__global__ void k_l4(const unsigned short* __restrict__ H3, const unsigned short* __restrict__ W4t,
                     const int* __restrict__ perm, const int* __restrict__ species,
                     const int* __restrict__ sidx, const float* __restrict__ coeff,
                     float* __restrict__ out) {
  int w = threadIdx.x >> 6, l = threadIdx.x & 63;
  int row = blockIdx.x * 4 + w;
  int src = perm[row];
  if (src < 0) return;
  int sp = species[src];
  us4 h = *(const us4*)&H3[(size_t)row * HIDDEN + l * 4];
  us4 wv = *(const us4*)&W4t[sp * HIDDEN + l * 4];
  float sum = 0.f;
#pragma unroll
  for (int e = 0; e < 4; ++e) sum += bf2f(h[e]) * bf2f(wv[e]);
#pragma unroll
  for (int d = 32; d >= 1; d >>= 1) sum += __shfl_xor(sum, d, 64);
  if (l == 0)
    atomicAdd(&out[sidx[src]], sum * (0.0625f * 0.125f) + coeff[sp]);
}

// ---- launcher -----------------------------------------------------------
extern "C" void kernel_launch(void* const* d_in, const int* in_sizes, int n_in,
                              void* d_out, int out_size, void* d_ws, size_t ws_size,
                              hipStream_t stream) {
  const float* features = (const float*)d_in[0];
  const float* W1 = (const float*)d_in[1];
  const float* W2 = (const float*)d_in[2];
  const float* W3 = (const float*)d_in[3];
  const float* W4 = (const float*)d_in[4];
  const float* coeff = (const float*)d_in[5];
  const int* species = (const int*)d_in[6];
  const int* sidx = (const int*)d_in[7];
  float* out = (float*)d_out;

  char* ws = (char*)d_ws;
  int* ints = (int*)(ws + WS_INTS);
  const float* zs = (const float*)(ws + 128);       // zero-stub (16 B used)
  int* perm = (int*)(ws + WS_PERM);
  unsigned short* W1t = (unsigned short*)(ws + WS_W1T);
  unsigned short* W2t = (unsigned short*)(ws + WS_W2T);
  unsigned short* W3t = (unsigned short*)(ws + WS_W3T);
  unsigned short* W4t = (unsigned short*)(ws + WS_W4T);
  unsigned short* H1 = (unsigned short*)(ws + WS_H1);
  unsigned short* H2 = (unsigned short*)(ws + WS_H2);
  float* Hp = (float*)(ws + WS_HP);

  // species bucketing
  k_init<<<(MPAD + 255) / 256, 256, 0, stream>>>(ints, perm, out);
  k_count<<<NATOMS / 256, 256, 0, stream>>>(species, ints);
  k_offsets<<<1, 1, 0, stream>>>(ints);
  k_scatter<<<NATOMS / 256, 256, 0, stream>>>(species, ints, perm);

  // weight prep for layer 1 (W2/W3 transposed after L1 — they alias W1t)
  k_transpose<<<NSPEC * (NFEAT / 64) * (HIDDEN / 64), 256, 0, stream>>>(W1, W1t, NFEAT, HIDDEN);
  k_w4<<<NSPEC, 256, 0, stream>>>(W4, W4t);
  k_zero<<<MPAD / 4, 256, 0, stream>>>(Hp);         // Hp := 0 (per call)

  const float s1 = 1.f / sqrtf((float)NFEAT);
  const float s2 = 1.f / 16.f;

  // layer 1: K-split, read-once, atomic f32 partials
  k_l1ks<<<NBLK1, 512, 0, stream>>>(features, W1t, Hp, perm, ints + 8, zs, s1);

  // W2/W3 prep (W1t region now dead)
  k_transpose<<<NSPEC * (HIDDEN / 64) * (HIDDEN / 64), 256, 0, stream>>>(W2, W2t, HIDDEN, HIDDEN);
  k_transpose<<<NSPEC * (HIDDEN / 64) * (HIDDEN / 64), 256, 0, stream>>>(W3, W3t, HIDDEN, HIDDEN);

  // layer 2 (f32 Hp + silu at load), layer 3 (bf16)
  k_mlp2<1><<<NBLK2, 256, 0, stream>>>(Hp, nullptr, W2t, H2, ints + 8, s2);
  k_mlp2<0><<<NBLK2, 256, 0, stream>>>(nullptr, H2, W3t, H1, ints + 8, s2);

  // layer 4 + segment sum + composition term
  k_l4<<<MPAD / 4, 256, 0, stream>>>(H1, W4t, perm, species, sidx, coeff, out);
}

// Round 12
// 237.024 us; speedup vs baseline: 1.2021x; 1.2021x over previous
//
#include <hip/hip_runtime.h>

// Problem constants (from reference setup_inputs)
#define NATOMS 32768
#define NFEAT 1920
#define HIDDEN 256
#define NSPEC 4
#define NSTRUCT 512
#define BK 32
#define MTILES 516               // 64-row m-tiles (4 species padded to x64)
#define MPAD (MTILES * 64)       // 33024
#define NBLK2 (MTILES * 2)       // layer-2/3 blocks (64-row tile, n-half)
#define KCH 384                  // L1 A-chunk (5 chunks; 1536-B row bursts)
#define NCH (NFEAT / KCH)        // 5
#define SUBS (KCH / BK)          // 12 substeps per chunk

typedef __bf16 bf16x8 __attribute__((ext_vector_type(8)));
typedef float f32x4 __attribute__((ext_vector_type(4)));
typedef float f4v __attribute__((ext_vector_type(4)));
typedef unsigned short us4 __attribute__((ext_vector_type(4)));

// Workspace layout (bytes). W2t/W3t alias W1t (transposed AFTER layer 1).
#define WS_INTS 0                                        // ints[0..3] counts,[4..7] cursors,[8..12] off
#define WS_PERM 256
#define WS_W1T (WS_PERM + MPAD * 4)
#define WS_W2T WS_W1T                                    // alias (post-L1)
#define WS_W3T (WS_W2T + NSPEC * HIDDEN * HIDDEN * 2)    // still inside W1t
#define WS_W4T (WS_W1T + NSPEC * HIDDEN * NFEAT * 2)
#define WS_H1  (WS_W4T + 4096)
#define WS_H2  (WS_H1 + (size_t)MPAD * HIDDEN * 2)       // end ~38 MB

__device__ __forceinline__ unsigned short f2bf(float f) {
  unsigned int u = __float_as_uint(f);
  u += 0x7fffu + ((u >> 16) & 1u);           // round-to-nearest-even
  return (unsigned short)(u >> 16);
}
__device__ __forceinline__ float bf2f(unsigned short s) {
  return __uint_as_float(((unsigned int)s) << 16);
}
__device__ __forceinline__ float silu_n(float x) {
  return (x / (1.f + __expf(-x))) * 1.6765f; // variance-preserving SiLU
}

// Direct global->LDS async copy, 16 B per lane. LDS dest = uniform base + lane*16.
__device__ __forceinline__ void gll16(const void* g, void* l) {
  __builtin_amdgcn_global_load_lds(
      (const __attribute__((address_space(1))) void*)g,
      (__attribute__((address_space(3))) void*)l, 16, 0, 0);
}

// ---- prep kernels -------------------------------------------------------

__global__ void k_init(int* ints, int* perm, float* out) {
  int i = blockIdx.x * blockDim.x + threadIdx.x;
  if (i < MPAD) perm[i] = -1;
  if (i < NSTRUCT) out[i] = 0.f;
  if (i < 8) ints[i] = 0;
}

// Block-aggregated species count: ballots -> LDS -> 4 atomics per block.
__global__ void k_count(const int* __restrict__ species, int* counts) {
  __shared__ int c[NSPEC];
  int tid = threadIdx.x;
  if (tid < NSPEC) c[tid] = 0;
  __syncthreads();
  int s = species[blockIdx.x * 256 + tid];
  int lane = tid & 63;
#pragma unroll
  for (int sp = 0; sp < NSPEC; ++sp) {
    unsigned long long m = __ballot(s == sp);
    if (lane == 0 && m) atomicAdd(&c[sp], __popcll(m));
  }
  __syncthreads();
  if (tid < NSPEC && c[tid]) atomicAdd(&counts[tid], c[tid]);
}

__global__ void k_offsets(int* ints) {
  int* counts = ints;
  int* cursors = ints + 4;
  int* off = ints + 8;
  off[0] = 0;
  for (int s = 0; s < NSPEC; ++s) {
    off[s + 1] = off[s] + ((counts[s] + 63) & ~63);    // pad to 64
    cursors[s] = off[s];
  }
}

// Block-aggregated scatter: one range-reserving atomic per (block, species).
__global__ void k_scatter(const int* __restrict__ species, int* ints, int* perm) {
  __shared__ int cnt[4][NSPEC];   // [wave][species]
  __shared__ int base[NSPEC];
  int tid = threadIdx.x;
  int w = tid >> 6, lane = tid & 63;
  int i = blockIdx.x * 256 + tid;
  int s = species[i];
  unsigned long long m0 = __ballot(s == 0);
  unsigned long long m1 = __ballot(s == 1);
  unsigned long long m2 = __ballot(s == 2);
  unsigned long long m3 = __ballot(s == 3);
  if (lane == 0) {
    cnt[w][0] = __popcll(m0);
    cnt[w][1] = __popcll(m1);
    cnt[w][2] = __popcll(m2);
    cnt[w][3] = __popcll(m3);
  }
  __syncthreads();
  if (tid < NSPEC) {
    int t = cnt[0][tid] + cnt[1][tid] + cnt[2][tid] + cnt[3][tid];
    base[tid] = t ? atomicAdd(&ints[4 + tid], t) : 0;
  }
  __syncthreads();
  unsigned long long mm = (s == 0) ? m0 : (s == 1) ? m1 : (s == 2) ? m2 : m3;
  int pos = base[s] + __popcll(mm & ((1ull << lane) - 1ull));
#pragma unroll
  for (int ww = 0; ww < 4; ++ww)
    if (ww < w) pos += cnt[ww][s];
  perm[pos] = i;
}

// f32 [S][K][N] -> bf16 [S][N][K]  (64x64 LDS tiled transpose)
__global__ void k_transpose(const float* __restrict__ src, unsigned short* __restrict__ dst,
                            int K, int N) {
  __shared__ unsigned short T[64][72];
  int ntN = N >> 6, ntK = K >> 6;
  int per = ntK * ntN;
  int b = blockIdx.x;
  int s = b / per, rem = b % per;
  int k0 = (rem / ntN) << 6;
  int n0 = (rem % ntN) << 6;
  int tid = threadIdx.x;
  int r = tid >> 2, cb = (tid & 3) << 4;
  const float* p = src + ((size_t)s * K + k0 + r) * N + n0 + cb;
#pragma unroll
  for (int j = 0; j < 16; j += 4) {
    f4v v = *(const f4v*)(p + j);
#pragma unroll
    for (int e = 0; e < 4; ++e) T[r][cb + j + e] = f2bf(v[e]);
  }
  __syncthreads();
  unsigned short* drow = dst + ((size_t)s * N + n0 + r) * K + k0 + cb;
#pragma unroll
  for (int j = 0; j < 4; ++j) {
    us4 o;
#pragma unroll
    for (int e = 0; e < 4; ++e) o[e] = T[cb + j * 4 + e][r];
    *(us4*)(drow + j * 4) = o;
  }
}

__global__ void k_w4(const float* __restrict__ src, unsigned short* __restrict__ dst) {
  int i = blockIdx.x * 256 + threadIdx.x;   // 4*256 elems
  dst[i] = f2bf(src[i]);
}

// ---- layer 1: contiguous-burst A, full-K, no atomics --------------------
// THEORY: every prior L1 was DRAM-granularity-bound (~1 TB/s: gathered rows
// touched in 128-B granules, page reopened each K-step). Here each atom row
// is read in 1536-B bursts (8 thr x 192 B contiguous), chunk KCH=384 held in
// LDS as bf16 (XOR-swizzled), B streamed per 32-k substep via gll16 dbuf.
// BM=64 x BN=256, 512 thr = 8 waves (2x4 of 32x64), grid 516 (~2/CU at 80 KB).
__global__ __launch_bounds__(512) void k_l1f(
    const float* __restrict__ xf, const unsigned short* __restrict__ Wt,
    unsigned short* __restrict__ Hout, const int* __restrict__ perm,
    const int* __restrict__ off, float scale) {
  __shared__ __align__(16) unsigned short Albs[64 * KCH];     // 48 KB (bf16 chunk)
  __shared__ __align__(16) unsigned short Blds[2 * 256 * 32]; // 32 KB dbuf

  // XCD-chunked bijective swizzle: consecutive lb on one XCD share species B.
  int nwg = gridDim.x;
  int xcd = blockIdx.x & 7, idx = blockIdx.x >> 3;
  int q = nwg >> 3, r = nwg & 7;
  int mt = (xcd < r ? xcd * (q + 1) : r * (q + 1) + (xcd - r) * q) + idx;

  int rowbase = mt * 64;
  int tid = threadIdx.x;
  int w = tid >> 6, lane = tid & 63;
  int wr = w >> 2, wc = w & 3;             // 8 waves: 2 row x 4 col of 32x64

  int sp;
  if (rowbase < off[1]) sp = 0;
  else if (rowbase < off[2]) sp = 1;
  else if (rowbase < off[3]) sp = 2;
  else sp = 3;

  // A loader: thread covers row=tid>>3, 48 consecutive f32 at (tid&7)*48.
  int arow = tid >> 3, aj = tid & 7;
  long as = perm[rowbase + arow];
  const float* ap = (as >= 0) ? (xf + (size_t)as * NFEAT + aj * 48) : nullptr;
  unsigned short* alw = Albs + arow * KCH;
  int agb = aj * 6;                        // granule base (16-B granules)
  int arx = arow & 7;                      // XOR key

  // B stage: 256 rows x 64 B = 16 chunks of 1 KB; wave w stages chunks 2w,2w+1.
  const unsigned short* srcB[2];
  int ldsB[2];
#pragma unroll
  for (int qq = 0; qq < 2; ++qq) {
    int c = w * 2 + qq;
    int row = c * 16 + (lane >> 2);
    int slot = (lane & 3) ^ ((row >> 2) & 3);
    srcB[qq] = Wt + ((size_t)(sp * HIDDEN + row)) * NFEAT + slot * 8;
    ldsB[qq] = c * 512;                    // shorts
  }
  auto STAGEB = [&](int b, int t) {
#pragma unroll
    for (int qq = 0; qq < 2; ++qq)
      gll16(srcB[qq] + t * BK, Blds + b * 8192 + ldsB[qq]);
  };

  f4v ar[12];
  auto LOADA = [&](int c) {
    if (ap) {
#pragma unroll
      for (int jj = 0; jj < 12; ++jj) ar[jj] = *(const f4v*)(ap + c * KCH + jj * 4);
    }
  };
  auto WRITEA = [&]() {
    if (ap) {
#pragma unroll
      for (int g = 0; g < 6; ++g) {
        unsigned r01, r23, r45, r67;
        asm("v_cvt_pk_bf16_f32 %0, %1, %2" : "=v"(r01) : "v"(ar[2 * g][0]), "v"(ar[2 * g][1]));
        asm("v_cvt_pk_bf16_f32 %0, %1, %2" : "=v"(r23) : "v"(ar[2 * g][2]), "v"(ar[2 * g][3]));
        asm("v_cvt_pk_bf16_f32 %0, %1, %2" : "=v"(r45) : "v"(ar[2 * g + 1][0]), "v"(ar[2 * g + 1][1]));
        asm("v_cvt_pk_bf16_f32 %0, %1, %2" : "=v"(r67) : "v"(ar[2 * g + 1][2]), "v"(ar[2 * g + 1][3]));
        uint4 u = {r01, r23, r45, r67};
        *(uint4*)(alw + ((agb + g) ^ arx) * 8) = u;
      }
    } else {
      uint4 z = {0, 0, 0, 0};
#pragma unroll
      for (int g = 0; g < 6; ++g) *(uint4*)(alw + ((agb + g) ^ arx) * 8) = z;
    }
  };

  f32x4 zero4 = {0.f, 0.f, 0.f, 0.f};
  f32x4 acc[2][4];
#pragma unroll
  for (int m = 0; m < 2; ++m)
#pragma unroll
    for (int n = 0; n < 4; ++n) acc[m][n] = zero4;

  int lr = lane & 15, lg = lane >> 4;

  LOADA(0);
  STAGEB(0, 0);
  int buf = 0;
  for (int c = 0; c < NCH; ++c) {
    WRITEA();                              // waits A regs, writes chunk c
    if (c + 1 < NCH) LOADA(c + 1);         // next chunk flies during 12 substeps
    __syncthreads();                       // A visible (drains B(0) of chunk too)
#pragma unroll
    for (int s = 0; s < SUBS; ++s) {
      int t = c * SUBS + s;
      if (t + 1 < NCH * SUBS) STAGEB(buf ^ 1, t + 1);

      bf16x8 a[2], b[4];
#pragma unroll
      for (int m = 0; m < 2; ++m) {
        int row = wr * 32 + m * 16 + lr;
        a[m] = *(const bf16x8*)(Albs + row * KCH + (((s * 4 + lg) ^ (row & 7)) << 3));
      }
#pragma unroll
      for (int n = 0; n < 4; ++n) {
        int row = wc * 64 + n * 16 + lr;
        b[n] = *(const bf16x8*)(Blds + buf * 8192 + row * 32 +
                                ((lg ^ ((row >> 2) & 3)) << 3));
      }
#pragma unroll
      for (int m = 0; m < 2; ++m)
#pragma unroll
        for (int n = 0; n < 4; ++n)
          acc[m][n] = __builtin_amdgcn_mfma_f32_16x16x32_bf16(a[m], b[n], acc[m][n], 0, 0, 0);

      __syncthreads();                     // drain B(t+1) + protect A/B reuse
      buf ^= 1;
    }
  }

  // epilogue: silu + bf16, D[row=wr*32+m*16+lg*4+rr][col=wc*64+n*16+lr]
#pragma unroll
  for (int m = 0; m < 2; ++m)
#pragma unroll
    for (int n = 0; n < 4; ++n)
#pragma unroll
      for (int rr = 0; rr < 4; ++rr) {
        float v = acc[m][n][rr] * scale;
        Hout[(size_t)(rowbase + wr * 32 + m * 16 + lg * 4 + rr) * HIDDEN +
             wc * 64 + n * 16 + lr] = f2bf(silu_n(v));
      }
}

// ---- layers 2/3: BM=64 x BN=128, 2-buffer drain (R8-proven) -------------
__global__ __launch_bounds__(256) void k_mlp2(
    const unsigned short* __restrict__ xb, const unsigned short* __restrict__ Wt,
    unsigned short* __restrict__ Hout, const int* __restrict__ off, float scale) {
  constexpr int K = HIDDEN;
  __shared__ __align__(16) unsigned short Asl[2 * 2048];
  __shared__ __align__(16) unsigned short Bsl[2 * 4096];
  unsigned short* ab = Asl;
  unsigned short* bl = Bsl;

  int nwg = gridDim.x;
  int xcd = blockIdx.x & 7, idx = blockIdx.x >> 3;
  int q = nwg >> 3, r = nwg & 7;
  int lb = (xcd < r ? xcd * (q + 1) : r * (q + 1) + (xcd - r) * q) + idx;
  int mt = lb >> 1, bn = lb & 1;

  int rowbase = mt * 64;
  int tid = threadIdx.x;
  int w = tid >> 6, lane = tid & 63;
  int wr = w >> 1, wc = w & 1;

  int sp;
  if (rowbase < off[1]) sp = 0;
  else if (rowbase < off[2]) sp = 1;
  else if (rowbase < off[3]) sp = 2;
  else sp = 3;

  const unsigned short* srcB[2];
  int ldsB[2];
#pragma unroll
  for (int qq = 0; qq < 2; ++qq) {
    int c = w * 2 + qq;
    int row = c * 16 + (lane >> 2);
    int slot = (lane & 3) ^ ((row >> 2) & 3);
    srcB[qq] = Wt + ((size_t)(sp * HIDDEN + bn * 128 + row)) * K + slot * 8;
    ldsB[qq] = c * 512;
  }
  int arow = w * 16 + (lane >> 2);
  int aslot = (lane & 3) ^ ((arow >> 2) & 3);
  const unsigned short* srcA1 = xb + ((size_t)(rowbase + arow)) * K + aslot * 8;
  int ldsA1 = w * 512;

  auto STAGE = [&](int b, int t) {
    gll16(srcA1 + t * BK, ab + b * 2048 + ldsA1);
#pragma unroll
    for (int qq = 0; qq < 2; ++qq)
      gll16(srcB[qq] + t * BK, bl + b * 4096 + ldsB[qq]);
  };

  f32x4 zero4 = {0.f, 0.f, 0.f, 0.f};
  f32x4 acc[2][4];
#pragma unroll
  for (int m = 0; m < 2; ++m)
#pragma unroll
    for (int n = 0; n < 4; ++n) acc[m][n] = zero4;

  int lr = lane & 15, lg = lane >> 4;
  constexpr int NT = K / BK;

  STAGE(0, 0);
  __syncthreads();
  int buf = 0;
  for (int t = 0; t < NT; ++t) {
    if (t + 1 < NT) STAGE(buf ^ 1, t + 1);

    bf16x8 a[2], b[4];
#pragma unroll
    for (int m = 0; m < 2; ++m) {
      int row = wr * 32 + m * 16 + lr;
      a[m] = *(const bf16x8*)(ab + buf * 2048 + row * 32 +
                              ((lg ^ ((row >> 2) & 3)) << 3));
    }
#pragma unroll
    for (int n = 0; n < 4; ++n) {
      int row = wc * 64 + n * 16 + lr;
      b[n] = *(const bf16x8*)(bl + buf * 4096 + row * 32 +
                              ((lg ^ ((row >> 2) & 3)) << 3));
    }
#pragma unroll
    for (int m = 0; m < 2; ++m)
#pragma unroll
      for (int n = 0; n < 4; ++n)
        acc[m][n] = __builtin_amdgcn_mfma_f32_16x16x32_bf16(a[m], b[n], acc[m][n], 0, 0, 0);

    __syncthreads();
    buf ^= 1;
  }

#pragma unroll
  for (int m = 0; m < 2; ++m)
#pragma unroll
    for (int n = 0; n < 4; ++n)
#pragma unroll
      for (int rr = 0; rr < 4; ++rr) {
        float v = acc[m][n][rr] * scale;
        Hout[(size_t)(rowbase + wr * 32 + m * 16 + lg * 4 + rr) * HIDDEN +
             bn * 128 + wc * 64 + n * 16 + lr] = f2bf(silu_n(v));
      }
}

// ---- layer 4 + segment reduction ---------------------------------------
__global__ void k_l4(const unsigned short* __restrict__ H3, const unsigned short* __restrict__ W4t,
                     const int* __restrict__ perm, const int* __restrict__ species,
                     const int* __restrict__ sidx, const float* __restrict__ coeff,
                     float* __restrict__ out) {
  int w = threadIdx.x >> 6, l = threadIdx.x & 63;
  int row = blockIdx.x * 4 + w;
  int src = perm[row];
  if (src < 0) return;
  int sp = species[src];
  us4 h = *(const us4*)&H3[(size_t)row * HIDDEN + l * 4];
  us4 wv = *(const us4*)&W4t[sp * HIDDEN + l * 4];
  float sum = 0.f;
#pragma unroll
  for (int e = 0; e < 4; ++e) sum += bf2f(h[e]) * bf2f(wv[e]);
#pragma unroll
  for (int d = 32; d >= 1; d >>= 1) sum += __shfl_xor(sum, d, 64);
  if (l == 0)
    atomicAdd(&out[sidx[src]], sum * (0.0625f * 0.125f) + coeff[sp]);
}

// ---- launcher -----------------------------------------------------------
extern "C" void kernel_launch(void* const* d_in, const int* in_sizes, int n_in,
                              void* d_out, int out_size, void* d_ws, size_t ws_size,
                              hipStream_t stream) {
  const float* features = (const float*)d_in[0];
  const float* W1 = (const float*)d_in[1];
  const float* W2 = (const float*)d_in[2];
  const float* W3 = (const float*)d_in[3];
  const float* W4 = (const float*)d_in[4];
  const float* coeff = (const float*)d_in[5];
  const int* species = (const int*)d_in[6];
  const int* sidx = (const int*)d_in[7];
  float* out = (float*)d_out;

  char* ws = (char*)d_ws;
  int* ints = (int*)(ws + WS_INTS);
  int* perm = (int*)(ws + WS_PERM);
  unsigned short* W1t = (unsigned short*)(ws + WS_W1T);
  unsigned short* W2t = (unsigned short*)(ws + WS_W2T);
  unsigned short* W3t = (unsigned short*)(ws + WS_W3T);
  unsigned short* W4t = (unsigned short*)(ws + WS_W4T);
  unsigned short* H1 = (unsigned short*)(ws + WS_H1);
  unsigned short* H2 = (unsigned short*)(ws + WS_H2);

  // species bucketing
  k_init<<<(MPAD + 255) / 256, 256, 0, stream>>>(ints, perm, out);
  k_count<<<NATOMS / 256, 256, 0, stream>>>(species, ints);
  k_offsets<<<1, 1, 0, stream>>>(ints);
  k_scatter<<<NATOMS / 256, 256, 0, stream>>>(species, ints, perm);

  // weight prep for layer 1 (W2/W3 transposed after L1 — they alias W1t)
  k_transpose<<<NSPEC * (NFEAT / 64) * (HIDDEN / 64), 256, 0, stream>>>(W1, W1t, NFEAT, HIDDEN);
  k_w4<<<NSPEC, 256, 0, stream>>>(W4, W4t);

  const float s1 = 1.f / sqrtf((float)NFEAT);
  const float s2 = 1.f / 16.f;

  // layer 1: contiguous-burst A, full-K in-register accumulation
  k_l1f<<<MTILES, 512, 0, stream>>>(features, W1t, H1, perm, ints + 8, s1);

  // W2/W3 prep (W1t region now dead)
  k_transpose<<<NSPEC * (HIDDEN / 64) * (HIDDEN / 64), 256, 0, stream>>>(W2, W2t, HIDDEN, HIDDEN);
  k_transpose<<<NSPEC * (HIDDEN / 64) * (HIDDEN / 64), 256, 0, stream>>>(W3, W3t, HIDDEN, HIDDEN);

  // layers 2, 3
  k_mlp2<<<NBLK2, 256, 0, stream>>>(H1, W2t, H2, ints + 8, s2);
  k_mlp2<<<NBLK2, 256, 0, stream>>>(H2, W3t, H1, ints + 8, s2);

  // layer 4 + segment sum + composition term
  k_l4<<<MPAD / 4, 256, 0, stream>>>(H1, W4t, perm, species, sidx, coeff, out);
}

// Round 13
// 200.133 us; speedup vs baseline: 1.4237x; 1.1843x over previous
//
#include <hip/hip_runtime.h>

// Problem constants (from reference setup_inputs)
#define NATOMS 32768
#define NFEAT 1920
#define HIDDEN 256
#define NSPEC 4
#define NSTRUCT 512
#define BM 64
#define BN 128
#define BK 32
#define MTILES 516               // max 64-row tiles (4 species padded to x64)
#define MPAD (MTILES * BM)       // 33024
#define NBLKG (MTILES * 2)       // 1032 blocks: (m-tile, n-half)

typedef __bf16 bf16x8 __attribute__((ext_vector_type(8)));
typedef float f32x4 __attribute__((ext_vector_type(4)));
typedef float f4v __attribute__((ext_vector_type(4)));
typedef unsigned short us4 __attribute__((ext_vector_type(4)));

// Workspace layout (bytes). W2t/W3t alias W1t (tiled AFTER layer 1).
#define WS_INTS 0                                        // ints[0..3] counts,[4..7] cursors,[8..12] off; bytes 128..191 zero-stub
#define WS_PERM 256
#define WS_W1T (WS_PERM + MPAD * 4)                      // 132352
#define WS_W2T WS_W1T                                    // alias (post-L1)
#define WS_W3T (WS_W2T + NSPEC * HIDDEN * HIDDEN * 2)    // still inside W1t
#define WS_W4T (WS_W1T + NSPEC * HIDDEN * NFEAT * 2)
#define WS_H1  (WS_W4T + 4096)
#define WS_H2  (WS_H1 + (size_t)MPAD * HIDDEN * 2)       // end ~38 MB

__device__ __forceinline__ unsigned short f2bf(float f) {
  unsigned int u = __float_as_uint(f);
  u += 0x7fffu + ((u >> 16) & 1u);           // round-to-nearest-even
  return (unsigned short)(u >> 16);
}
__device__ __forceinline__ float bf2f(unsigned short s) {
  return __uint_as_float(((unsigned int)s) << 16);
}
__device__ __forceinline__ float silu_n(float x) {
  return (x / (1.f + __expf(-x))) * 1.6765f; // variance-preserving SiLU
}

// Direct global->LDS async copy, 16 B per lane. LDS dest = uniform base + lane*16.
__device__ __forceinline__ void gll16(const void* g, void* l) {
  __builtin_amdgcn_global_load_lds(
      (const __attribute__((address_space(1))) void*)g,
      (__attribute__((address_space(3))) void*)l, 16, 0, 0);
}

// ---- prep kernels -------------------------------------------------------

__global__ void k_init(int* ints, int* perm, float* out) {
  int i = blockIdx.x * blockDim.x + threadIdx.x;
  if (i < MPAD) perm[i] = -1;
  if (i < NSTRUCT) out[i] = 0.f;
  if (i < 8) ints[i] = 0;
  if (i >= 32 && i < 48) ((float*)ints)[i] = 0.f;   // zero-stub for padded gather rows
}

// Block-aggregated species count: ballots -> LDS -> 4 atomics per block.
__global__ void k_count(const int* __restrict__ species, int* counts) {
  __shared__ int c[NSPEC];
  int tid = threadIdx.x;
  if (tid < NSPEC) c[tid] = 0;
  __syncthreads();
  int s = species[blockIdx.x * 256 + tid];
  int lane = tid & 63;
#pragma unroll
  for (int sp = 0; sp < NSPEC; ++sp) {
    unsigned long long m = __ballot(s == sp);
    if (lane == 0 && m) atomicAdd(&c[sp], __popcll(m));
  }
  __syncthreads();
  if (tid < NSPEC && c[tid]) atomicAdd(&counts[tid], c[tid]);
}

__global__ void k_offsets(int* ints) {
  int* counts = ints;
  int* cursors = ints + 4;
  int* off = ints + 8;
  off[0] = 0;
  for (int s = 0; s < NSPEC; ++s) {
    off[s + 1] = off[s] + ((counts[s] + 63) & ~63);    // pad to BM=64
    cursors[s] = off[s];
  }
}

// Block-aggregated scatter: one range-reserving atomic per (block, species).
__global__ void k_scatter(const int* __restrict__ species, int* ints, int* perm) {
  __shared__ int cnt[4][NSPEC];   // [wave][species]
  __shared__ int base[NSPEC];
  int tid = threadIdx.x;
  int w = tid >> 6, lane = tid & 63;
  int i = blockIdx.x * 256 + tid;
  int s = species[i];
  unsigned long long m0 = __ballot(s == 0);
  unsigned long long m1 = __ballot(s == 1);
  unsigned long long m2 = __ballot(s == 2);
  unsigned long long m3 = __ballot(s == 3);
  if (lane == 0) {
    cnt[w][0] = __popcll(m0);
    cnt[w][1] = __popcll(m1);
    cnt[w][2] = __popcll(m2);
    cnt[w][3] = __popcll(m3);
  }
  __syncthreads();
  if (tid < NSPEC) {
    int t = cnt[0][tid] + cnt[1][tid] + cnt[2][tid] + cnt[3][tid];
    base[tid] = t ? atomicAdd(&ints[4 + tid], t) : 0;
  }
  __syncthreads();
  unsigned long long mm = (s == 0) ? m0 : (s == 1) ? m1 : (s == 2) ? m2 : m3;
  int pos = base[s] + __popcll(mm & ((1ull << lane) - 1ull));
#pragma unroll
  for (int ww = 0; ww < 4; ++ww)
    if (ww < w) pos += cnt[ww][s];
  perm[pos] = i;
}

// f32 [S][K][N=256] -> bf16 TILED STAGING LAYOUT:
// Wt[sp][t=k/32][chunk=n/16][lane 0..63][8 shorts], where
//   lane = (n&15)*4 | (kgranule ^ ((n>>2)&3)),  kgranule = (k>>3)&3.
// Every consumer gll16 then reads a CONTIGUOUS 1-KB-aligned 1-KB burst, and
// the LDS image (incl. XOR bank swizzle) is bit-identical to the previous
// scattered-source version — only the DRAM access order changes.
__global__ void k_wtile(const float* __restrict__ src, unsigned short* __restrict__ dst,
                        int K, int N) {
  __shared__ unsigned short T[64][72];
  int ntN = N >> 6, ntK = K >> 6;
  int per = ntK * ntN;
  int b = blockIdx.x;
  int s = b / per, rem = b % per;
  int k0 = (rem / ntN) << 6;
  int n0 = (rem % ntN) << 6;
  int tid = threadIdx.x;
  int r = tid >> 2, cb = (tid & 3) << 4;
  const float* p = src + ((size_t)s * K + k0 + r) * N + n0 + cb;
#pragma unroll
  for (int j = 0; j < 16; j += 4) {
    f4v v = *(const f4v*)(p + j);
#pragma unroll
    for (int e = 0; e < 4; ++e) T[r][cb + j + e] = f2bf(v[e]);   // T[k-local][n-local]
  }
  __syncthreads();
  unsigned short* base = dst + (size_t)s * HIDDEN * K;   // per-species (256 rows)
  int row_n = n0 + r;
#pragma unroll
  for (int g2 = 0; g2 < 2; ++g2) {
    int kl = cb + g2 * 8;                 // k-local (granule of 8)
    int kg = k0 + kl;                     // global k
    int t = kg >> 5;
    int kgl = (kg >> 3) & 3;
    int lanepos = ((row_n & 15) << 2) | (kgl ^ ((row_n >> 2) & 3));
    unsigned short v[8];
#pragma unroll
    for (int e = 0; e < 8; ++e) v[e] = T[kl + e][r];
    uint4 u;
    u.x = v[0] | ((unsigned)v[1] << 16);
    u.y = v[2] | ((unsigned)v[3] << 16);
    u.z = v[4] | ((unsigned)v[5] << 16);
    u.w = v[6] | ((unsigned)v[7] << 16);
    *(uint4*)(base + (size_t)t * 8192 + ((row_n >> 4) << 9) + lanepos * 8) = u;
  }
}

__global__ void k_w4(const float* __restrict__ src, unsigned short* __restrict__ dst) {
  int i = blockIdx.x * 256 + threadIdx.x;   // 4*256 elems
  dst[i] = f2bf(src[i]);
}

// ---- grouped MFMA GEMM layer (R8 geometry; B source now CONTIGUOUS) -----
// X[Mpad x K] @ Wtiled[sp] -> H[Mpad x 256], silu_n epilogue.
// 256 thr = 4 waves (2x2 of 32x64); tile BM=64 x BN=128 x BK=32; grid 1032.
// Double-buffered gll16 staging, drain sync. B gll16s read 1-KB contiguous
// chunks from the tiled W layout; LDS image identical to R8.
template <int K, bool AF32>
__global__ __launch_bounds__(256) void k_mlp(
    const float* __restrict__ xf, const unsigned short* __restrict__ xb,
    const unsigned short* __restrict__ Wt, unsigned short* __restrict__ Hout,
    const int* __restrict__ perm, const int* __restrict__ off,
    const float* __restrict__ zs, float scale) {
  __shared__ __align__(16) unsigned short Asl[AF32 ? 2 * 64 * 64 : 2 * 64 * 32];
  __shared__ __align__(16) unsigned short Bsl[2 * 128 * 32];
  float* af = (float*)Asl;                 // f32 view (AF32)
  unsigned short* ab = Asl;                // bf16 view
  unsigned short* bl = Bsl;

  // XCD-chunked bijective swizzle: consecutive lb (same XCD) = the two
  // n-halves of one m-tile -> shared A panel hits L2.
  int nwg = gridDim.x;
  int xcd = blockIdx.x & 7, idx = blockIdx.x >> 3;
  int q = nwg >> 3, r = nwg & 7;
  int lb = (xcd < r ? xcd * (q + 1) : r * (q + 1) + (xcd - r) * q) + idx;
  int mt = lb >> 1, bn = lb & 1;

  int rowbase = mt * BM;
  int tid = threadIdx.x;
  int w = tid >> 6, lane = tid & 63;
  int wr = w >> 1, wc = w & 1;             // wave -> (row-half, col-half) of 32x64

  int sp;
  if (rowbase < off[1]) sp = 0;
  else if (rowbase < off[2]) sp = 1;
  else if (rowbase < off[3]) sp = 2;
  else sp = 3;

  // ---- staging descriptors ----
  // B: tiled layout; wave w stages chunks c=2w,2w+1 (global chunk bn*8+c).
  // Each gll16 source is CONTIGUOUS: chunk base + lane*16 B.
  const unsigned short* srcB[2];
  int ldsB[2];
#pragma unroll
  for (int qq = 0; qq < 2; ++qq) {
    int c = w * 2 + qq;
    int gc = bn * 8 + c;
    srcB[qq] = Wt + (size_t)sp * HIDDEN * K + gc * 512 + lane * 8;
    ldsB[qq] = c * 512;                    // shorts
  }
  // A tile:
  const float* srcA[2];
  const unsigned short* srcA1 = nullptr;
  int ldsA[2], ldsA1 = 0;
  if constexpr (AF32) {
    // 64 rows x 128 B = 8 chunks of 1 KB (8 rows each); wave w: chunks 2w,2w+1.
#pragma unroll
    for (int qq = 0; qq < 2; ++qq) {
      int c = w * 2 + qq;
      int row = c * 8 + (lane >> 3);       // 0..63
      int slot = (lane & 7) ^ (row & 7);
      long as = perm[rowbase + row];
      srcA[qq] = (as >= 0) ? (xf + (size_t)as * K + slot * 4) : nullptr;
      ldsA[qq] = c * 256;                  // floats
    }
  } else {
    // 64 rows x 64 B = 4 chunks of 1 KB (16 rows each); wave w: chunk w.
    int row = w * 16 + (lane >> 2);        // 0..63
    int slot = (lane & 3) ^ ((row >> 2) & 3);
    srcA1 = xb + ((size_t)(rowbase + row)) * K + slot * 8;
    ldsA1 = w * 512;                       // shorts
  }

  auto STAGE = [&](int b, int t) {
    if constexpr (AF32) {
#pragma unroll
      for (int qq = 0; qq < 2; ++qq) {
        const float* s = srcA[qq] ? srcA[qq] + t * BK : zs;
        gll16(s, af + b * 2048 + ldsA[qq]);
      }
    } else {
      gll16(srcA1 + t * BK, ab + b * 2048 + ldsA1);
    }
#pragma unroll
    for (int qq = 0; qq < 2; ++qq)
      gll16(srcB[qq] + (size_t)t * 8192, bl + b * 4096 + ldsB[qq]);
  };

  f32x4 zero4 = {0.f, 0.f, 0.f, 0.f};
  f32x4 acc[2][4];
#pragma unroll
  for (int m = 0; m < 2; ++m)
#pragma unroll
    for (int n = 0; n < 4; ++n) acc[m][n] = zero4;

  int lr = lane & 15, lg = lane >> 4;
  constexpr int NT = K / BK;

  STAGE(0, 0);
  __syncthreads();
  int buf = 0;
  for (int t = 0; t < NT; ++t) {
    if (t + 1 < NT) STAGE(buf ^ 1, t + 1);

    bf16x8 a[2], b[4];
#pragma unroll
    for (int m = 0; m < 2; ++m) {
      int row = wr * 32 + m * 16 + lr;
      if constexpr (AF32) {
        const float* base = af + buf * 2048 + row * 32;
        f4v x0 = *(const f4v*)(base + (((lg << 1) ^ (row & 7)) << 2));
        f4v x1 = *(const f4v*)(base + ((((lg << 1) | 1) ^ (row & 7)) << 2));
        unsigned r01, r23, r45, r67;
        asm("v_cvt_pk_bf16_f32 %0, %1, %2" : "=v"(r01) : "v"(x0[0]), "v"(x0[1]));
        asm("v_cvt_pk_bf16_f32 %0, %1, %2" : "=v"(r23) : "v"(x0[2]), "v"(x0[3]));
        asm("v_cvt_pk_bf16_f32 %0, %1, %2" : "=v"(r45) : "v"(x1[0]), "v"(x1[1]));
        asm("v_cvt_pk_bf16_f32 %0, %1, %2" : "=v"(r67) : "v"(x1[2]), "v"(x1[3]));
        union { unsigned u[4]; bf16x8 v; } cv = {{r01, r23, r45, r67}};
        a[m] = cv.v;
      } else {
        a[m] = *(const bf16x8*)(ab + buf * 2048 + row * 32 +
                                ((lg ^ ((row >> 2) & 3)) << 3));
      }
    }
#pragma unroll
    for (int n = 0; n < 4; ++n) {
      int row = wc * 64 + n * 16 + lr;     // 0..127 within B tile
      b[n] = *(const bf16x8*)(bl + buf * 4096 + row * 32 +
                              ((lg ^ ((row >> 2) & 3)) << 3));
    }
#pragma unroll
    for (int m = 0; m < 2; ++m)
#pragma unroll
      for (int n = 0; n < 4; ++n)
        acc[m][n] = __builtin_amdgcn_mfma_f32_16x16x32_bf16(a[m], b[n], acc[m][n], 0, 0, 0);

    __syncthreads();                       // drain (t+1 staged) + barrier
    buf ^= 1;
  }

  // epilogue: D[row=wr*32+m*16+lg*4+rr][col=bn*128+wc*64+n*16+lr]
#pragma unroll
  for (int m = 0; m < 2; ++m)
#pragma unroll
    for (int n = 0; n < 4; ++n)
#pragma unroll
      for (int rr = 0; rr < 4; ++rr) {
        float v = acc[m][n][rr] * scale;
        Hout[(size_t)(rowbase + wr * 32 + m * 16 + lg * 4 + rr) * HIDDEN +
             bn * BN + wc * 64 + n * 16 + lr] = f2bf(silu_n(v));
      }
}

// ---- layer 4 + segment reduction ---------------------------------------
__global__ void k_l4(const unsigned short* __restrict__ H3, const unsigned short* __restrict__ W4t,
                     const int* __restrict__ perm, const int* __restrict__ species,
                     const int* __restrict__ sidx, const float* __restrict__ coeff,
                     float* __restrict__ out) {
  int w = threadIdx.x >> 6, l = threadIdx.x & 63;
  int row = blockIdx.x * 4 + w;
  int src = perm[row];
  if (src < 0) return;
  int sp = species[src];
  us4 h = *(const us4*)&H3[(size_t)row * HIDDEN + l * 4];
  us4 wv = *(const us4*)&W4t[sp * HIDDEN + l * 4];
  float sum = 0.f;
#pragma unroll
  for (int e = 0; e < 4; ++e) sum += bf2f(h[e]) * bf2f(wv[e]);
#pragma unroll
  for (int d = 32; d >= 1; d >>= 1) sum += __shfl_xor(sum, d, 64);
  if (l == 0)
    atomicAdd(&out[sidx[src]], sum * (0.0625f * 0.125f) + coeff[sp]);
}

// ---- launcher -----------------------------------------------------------
extern "C" void kernel_launch(void* const* d_in, const int* in_sizes, int n_in,
                              void* d_out, int out_size, void* d_ws, size_t ws_size,
                              hipStream_t stream) {
  const float* features = (const float*)d_in[0];
  const float* W1 = (const float*)d_in[1];
  const float* W2 = (const float*)d_in[2];
  const float* W3 = (const float*)d_in[3];
  const float* W4 = (const float*)d_in[4];
  const float* coeff = (const float*)d_in[5];
  const int* species = (const int*)d_in[6];
  const int* sidx = (const int*)d_in[7];
  float* out = (float*)d_out;

  char* ws = (char*)d_ws;
  int* ints = (int*)(ws + WS_INTS);
  const float* zs = (const float*)(ws + 128);       // zero-stub (16 B used)
  int* perm = (int*)(ws + WS_PERM);
  unsigned short* W1t = (unsigned short*)(ws + WS_W1T);
  unsigned short* W2t = (unsigned short*)(ws + WS_W2T);
  unsigned short* W3t = (unsigned short*)(ws + WS_W3T);
  unsigned short* W4t = (unsigned short*)(ws + WS_W4T);
  unsigned short* H1 = (unsigned short*)(ws + WS_H1);
  unsigned short* H2 = (unsigned short*)(ws + WS_H2);

  // species bucketing
  k_init<<<(MPAD + 255) / 256, 256, 0, stream>>>(ints, perm, out);
  k_count<<<NATOMS / 256, 256, 0, stream>>>(species, ints);
  k_offsets<<<1, 1, 0, stream>>>(ints);
  k_scatter<<<NATOMS / 256, 256, 0, stream>>>(species, ints, perm);

  // weight prep for layer 1 (W2/W3 tiled after L1 — they alias W1t)
  k_wtile<<<NSPEC * (NFEAT / 64) * (HIDDEN / 64), 256, 0, stream>>>(W1, W1t, NFEAT, HIDDEN);
  k_w4<<<NSPEC, 256, 0, stream>>>(W4, W4t);

  const float s1 = 1.f / sqrtf((float)NFEAT);
  const float s2 = 1.f / 16.f;

  // layer 1 (f32 gather -> bf16 MFMA)
  k_mlp<NFEAT, true><<<NBLKG, 256, 0, stream>>>(features, nullptr, W1t, H1, perm, ints + 8, zs, s1);

  // W2/W3 prep (W1t region now dead)
  k_wtile<<<NSPEC * (HIDDEN / 64) * (HIDDEN / 64), 256, 0, stream>>>(W2, W2t, HIDDEN, HIDDEN);
  k_wtile<<<NSPEC * (HIDDEN / 64) * (HIDDEN / 64), 256, 0, stream>>>(W3, W3t, HIDDEN, HIDDEN);

  // layers 2, 3
  k_mlp<HIDDEN, false><<<NBLKG, 256, 0, stream>>>(nullptr, H1, W2t, H2, perm, ints + 8, zs, s2);
  k_mlp<HIDDEN, false><<<NBLKG, 256, 0, stream>>>(nullptr, H2, W3t, H1, perm, ints + 8, zs, s2);

  // layer 4 + segment sum + composition term
  k_l4<<<MPAD / 4, 256, 0, stream>>>(H1, W4t, perm, species, sidx, coeff, out);
}